// Round 11
// baseline (278.768 us; speedup 1.0000x reference)
//
#include <hip/hip_runtime.h>
#include <cstddef>
#include <cstdint>

namespace {

constexpr int   kN = 512;
constexpr int   kB = 64;
constexpr float kAlpha = 0.8f;
constexpr float kBig  = 1e8f;
constexpr float kKexp = 144.26950408889634f;    // (1/gamma) * log2(e)
constexpr float kGLn2 = 0.006931471805599453f;  // gamma * ln(2)
constexpr float kWexp = 0.07213475204444817f;   // G * log2(e)

constexpr int W     = 8;     // waves per block (2 per SIMD — latency hiding)
constexpr int DELTA = 16;    // global steps between block barriers
constexpr int LAM   = 80;    // per-wave lag = 64 + DELTA
constexpr int SMAX  = 574;   // last local step per wave (inclusive)
constexpr int GTOT  = 1136;  // 71 supersteps cover g = 0..1134

// Single forward pass computing (R, Rdot): Rdot = JVP of soft-DTW in the
// direction Omega_ij = (i-j)^2; loss_temporal = Rdot[N,N]/N^2. No backward
// pass, no scratch traffic. 8 staggered waves per batch; wave w owns rows
// [64w, 64w+64); lane u owns the single row gi = 64w+u. Step s: col c = s-u.
__global__ __launch_bounds__(512)
void dilate_jvp8(const float* __restrict__ input,
                 const float* __restrict__ target,
                 float* __restrict__ partials,
                 int b0)
{
    __shared__ float sx[kN];
    __shared__ float ringR[W][128];   // row-boundary R
    __shared__ float ringD[W][128];   // row-boundary Rdot
    __shared__ float sred[W];

    const int tid = (int)threadIdx.x;
    const int w = tid >> 6, u = tid & 63;
    const int wprev = (w > 0) ? (w - 1) : 0;
    const bool topw = (w == 0);
    const int b = b0 + (int)blockIdx.x;
    const int sOff = w * LAM;
    const int gi = tid;               // 0-based global row

    sx[tid] = input[(size_t)b * kN + tid];
    const float tk = target[(size_t)b * kN + tid];

    // normalized exponential time weight for row gi
    float ew = exp2f(kWexp * (float)gi);
    float es = ew;
    #pragma unroll
    for (int off = 32; off; off >>= 1) es += __shfl_xor(es, off);
    if (u == 0) sred[w] = es;
    __syncthreads();
    float tot = 0.0f;
    #pragma unroll
    for (int q = 0; q < W; ++q) tot += sred[q];
    const float wk = ew * (512.0f / tot);

    // ================= forward soft-DTW with dual (JVP) =================
    float C0 = kBig, C0d = 0.0f;                  // own row, previous column
    float aval = kBig, bval = kBig;               // row above: cols c-1, c
    float avald = 0.0f, bvald = 0.0f;
    float prevRB = kBig, prevRBd = 0.0f;
    float xj = sx[0];

    for (int m = 0; m < GTOT / DELTA; ++m) {
        #pragma unroll
        for (int dg = 0; dg < DELTA; ++dg) {
            const int s = m * DELTA + dg - sOff;
            if (s >= 0 && s <= SMAX) {
                const int c = s - u;
                const bool valid = (c >= 0) & (c <= 511);
                const float rB  = ringR[wprev][s & 127];
                const float rBd = ringD[wprev][s & 127];
                float Acur, Bcur, Ad, Bd;
                if (u == 0) {
                    if (topw) { Bcur = kBig; Bd = 0.0f;
                                Acur = (s == 0) ? 0.0f : kBig; Ad = 0.0f; }
                    else      { Bcur = rB; Bd = rBd;
                                Acur = prevRB; Ad = prevRBd; }
                } else { Acur = aval; Ad = avald; Bcur = bval; Bd = bvald; }
                prevRB = rB; prevRBd = rBd;
                const float fd = (float)(64 * w + 2 * u - s);  // i - j
                const float m0  = fminf(Bcur, fminf(Acur, C0));
                const float mk0 = m0 * kKexp;
                const float eA0 = exp2f(fmaf(-kKexp, Acur, mk0));
                const float eB0 = exp2f(fmaf(-kKexp, Bcur, mk0));
                const float eC0 = exp2f(fmaf(-kKexp, C0,   mk0));
                const float ss0 = eA0 + eB0 + eC0;
                const float ri0 = __builtin_amdgcn_rcpf(ss0);
                const float dx0 = tk - xj;
                float cur  = fmaf(wk * dx0, dx0, m0 - kGLn2 * __log2f(ss0));
                const float sd0 = fmaf(eA0, Ad, fmaf(eB0, Bd, eC0 * C0d));
                float curd = fmaf(ri0, sd0, fd * fd);
                cur  = valid ? cur  : kBig;
                curd = valid ? curd : 0.0f;
                C0 = cur; C0d = curd;
                if (u == 63 && valid) {
                    ringR[w][c & 127] = cur;
                    ringD[w][c & 127] = curd;
                }
                aval = bval; avald = bvald;
                bval  = __shfl_up(C0, 1);
                bvald = __shfl_up(C0d, 1);
                int cn = c + 1; cn = cn < 0 ? 0 : (cn > 511 ? 511 : cn);
                xj = sx[cn];
            }
        }
        __syncthreads();
    }

    // tid 511 (wave 7, lane 63) holds R[512][512] and Rdot[512][512]
    if (tid == 511) {
        const float temporal = C0d * (1.0f / (512.0f * 512.0f));
        partials[b] = (kAlpha * C0 + (1.0f - kAlpha) * temporal)
                    * (1.0f / (float)kB);
    }
}

__global__ void dilate_finalize(const float* __restrict__ partials,
                                float* __restrict__ out) {
    float v = partials[threadIdx.x];   // 64 threads = one wave
    #pragma unroll
    for (int off = 32; off > 0; off >>= 1) v += __shfl_down(v, off);
    if (threadIdx.x == 0) out[0] = v;
}

} // namespace

extern "C" void kernel_launch(void* const* d_in, const int* in_sizes, int n_in,
                              void* d_out, int out_size, void* d_ws, size_t ws_size,
                              hipStream_t stream) {
    (void)in_sizes; (void)n_in; (void)out_size; (void)ws_size;
    const float* input  = (const float*)d_in[0];
    const float* target = (const float*)d_in[1];
    float* out      = (float*)d_out;
    float* partials = (float*)d_ws;    // kB floats

    hipLaunchKernelGGL(dilate_jvp8, dim3(kB), dim3(512), 0, stream,
                       input, target, partials, 0);
    hipLaunchKernelGGL(dilate_finalize, dim3(1), dim3(64), 0, stream,
                       partials, out);
}

// Round 12
// 251.596 us; speedup vs baseline: 1.1080x; 1.1080x over previous
//
#include <hip/hip_runtime.h>
#include <cstddef>
#include <cstdint>

namespace {

constexpr int   kN = 512;
constexpr int   kB = 64;
constexpr float kAlpha = 0.8f;
constexpr float kBig  = 1e8f;
constexpr float kKexp = 144.26950408889634f;    // (1/gamma) * log2(e)
constexpr float kGLn2 = 0.006931471805599453f;  // gamma * ln(2)
constexpr float kWexp = 0.07213475204444817f;   // G * log2(e)

constexpr int W     = 8;     // waves per block (2 per SIMD)
constexpr int DELTA = 16;    // global steps between block barriers
constexpr int LAM   = 80;    // per-wave lag = 64 + DELTA
constexpr int SMAX  = 574;   // last local step per wave (inclusive)
constexpr int GTOT  = 1136;  // 71 supersteps cover g = 0..1134

// lane u <- lane u-1 (whole-wave shift; lane 0 keeps own, always overridden)
__device__ __forceinline__ float dpp_shr1(float x) {
    const int xi = __builtin_bit_cast(int, x);
    const int r  = __builtin_amdgcn_update_dpp(xi, xi, 0x138, 0xF, 0xF, false);
    return __builtin_bit_cast(float, r);
}

// Single forward pass computing (R, Rdot): Rdot = JVP of soft-DTW in the
// direction Omega_ij = (i-j)^2; loss_temporal = Rdot[N,N]/N^2.
// 8 staggered waves per batch; wave w owns rows [64w,64w+64); lane u owns row
// 64w+u. Step s: column c = s-u. Cross-wave boundary via prefetched LDS ring;
// cross-lane via DPP (VALU latency, not LDS).
__global__ __launch_bounds__(512)
void dilate_jvp8(const float* __restrict__ input,
                 const float* __restrict__ target,
                 float* __restrict__ partials,
                 int b0)
{
    __shared__ float  sx[kN];
    __shared__ float2 ring[W][128];   // {R, Rdot} row-boundary
    __shared__ float  sred[W];

    const int tid = (int)threadIdx.x;
    const int w = tid >> 6, u = tid & 63;
    const int wprev = (w > 0) ? (w - 1) : 0;
    const bool topw = (w == 0);
    const int b = b0 + (int)blockIdx.x;
    const int sOff = w * LAM;

    sx[tid] = input[(size_t)b * kN + tid];
    const float tk = target[(size_t)b * kN + tid];

    // normalized exponential time weight for row tid
    float ew = exp2f(kWexp * (float)tid);
    float es = ew;
    #pragma unroll
    for (int off = 32; off; off >>= 1) es += __shfl_xor(es, off);
    if (u == 0) sred[w] = es;
    __syncthreads();
    float tot = 0.0f;
    #pragma unroll
    for (int q = 0; q < W; ++q) tot += sred[q];
    const float wk = ew * (512.0f / tot);

    // ================= forward soft-DTW with dual (JVP) =================
    float C0 = kBig, C0d = 0.0f;                  // own row, previous column
    float aval = kBig, bval = kBig;               // row above: cols c-1, c
    float avald = 0.0f, bvald = 0.0f;
    float prevRB = kBig, prevRBd = 0.0f;
    float2 rn = make_float2(kBig, 0.0f);          // prefetched ring (for next s)
    float xj  = sx[0];
    float xjn = sx[(u == 0) ? 1 : 0];
    float fdr = (float)(64 * w + 2 * u);          // i - j at s=0, rolls down

    for (int m = 0; m < GTOT / DELTA; ++m) {
        #pragma unroll
        for (int dg = 0; dg < DELTA; ++dg) {
            const int s = m * DELTA + dg - sOff;
            if (s >= -1 && s <= SMAX) {
                const float2 rcur = rn;
                rn = ring[wprev][(s + 1) & 127];   // prefetch next slot early
                if (s >= 0) {
                    const int c = s - u;
                    const bool valid = (c >= 0) & (c <= 511);
                    float Acur, Bcur, Ad, Bd;
                    if (u == 0) {
                        if (topw) { Bcur = kBig; Bd = 0.0f;
                                    Acur = (s == 0) ? 0.0f : kBig; Ad = 0.0f; }
                        else      { Bcur = rcur.x; Bd = rcur.y;
                                    Acur = prevRB; Ad = prevRBd; }
                    } else { Acur = aval; Ad = avald; Bcur = bval; Bd = bvald; }
                    prevRB = rcur.x; prevRBd = rcur.y;
                    const float m0  = fminf(Bcur, fminf(Acur, C0));
                    const float mk0 = m0 * kKexp;
                    const float eA0 = exp2f(fmaf(-kKexp, Acur, mk0));
                    const float eB0 = exp2f(fmaf(-kKexp, Bcur, mk0));
                    const float eC0 = exp2f(fmaf(-kKexp, C0,   mk0));
                    const float ss0 = eA0 + eB0 + eC0;
                    const float ri0 = __builtin_amdgcn_rcpf(ss0);
                    const float dx0 = tk - xj;
                    float cur  = fmaf(wk * dx0, dx0, m0 - kGLn2 * __log2f(ss0));
                    const float sd0 = fmaf(eA0, Ad, fmaf(eB0, Bd, eC0 * C0d));
                    float curd = fmaf(ri0, sd0, fdr * fdr);
                    cur  = valid ? cur  : kBig;
                    curd = valid ? curd : 0.0f;
                    C0 = cur; C0d = curd;
                    if (u == 63) ring[w][c & 127] = make_float2(cur, curd);
                    aval = bval; avald = bvald;
                    bval  = dpp_shr1(C0);
                    bvald = dpp_shr1(C0d);
                    xj = xjn;
                    int cc = c + 2; cc = cc < 0 ? 0 : (cc > 511 ? 511 : cc);
                    xjn = sx[cc];
                    fdr -= 1.0f;
                }
            }
        }
        __syncthreads();
    }

    // tid 511 (wave 7, lane 63) holds R[512][512] and Rdot[512][512]
    if (tid == 511) {
        const float temporal = C0d * (1.0f / (512.0f * 512.0f));
        partials[b] = (kAlpha * C0 + (1.0f - kAlpha) * temporal)
                    * (1.0f / (float)kB);
    }
}

__global__ void dilate_finalize(const float* __restrict__ partials,
                                float* __restrict__ out) {
    float v = partials[threadIdx.x];   // 64 threads = one wave
    #pragma unroll
    for (int off = 32; off > 0; off >>= 1) v += __shfl_down(v, off);
    if (threadIdx.x == 0) out[0] = v;
}

} // namespace

extern "C" void kernel_launch(void* const* d_in, const int* in_sizes, int n_in,
                              void* d_out, int out_size, void* d_ws, size_t ws_size,
                              hipStream_t stream) {
    (void)in_sizes; (void)n_in; (void)out_size; (void)ws_size;
    const float* input  = (const float*)d_in[0];
    const float* target = (const float*)d_in[1];
    float* out      = (float*)d_out;
    float* partials = (float*)d_ws;    // kB floats

    hipLaunchKernelGGL(dilate_jvp8, dim3(kB), dim3(512), 0, stream,
                       input, target, partials, 0);
    hipLaunchKernelGGL(dilate_finalize, dim3(1), dim3(64), 0, stream,
                       partials, out);
}

// Round 13
// 215.190 us; speedup vs baseline: 1.2955x; 1.1692x over previous
//
#include <hip/hip_runtime.h>
#include <cstddef>
#include <cstdint>

namespace {

constexpr int   kN = 512;
constexpr int   kB = 64;
constexpr float kAlpha = 0.8f;
constexpr float kBig  = 1e8f;
constexpr float kKexp = 144.26950408889634f;    // (1/gamma) * log2(e)
constexpr float kGLn2 = 0.006931471805599453f;  // gamma * ln(2)
constexpr float kWexp = 0.07213475204444817f;   // G * log2(e)

constexpr int W     = 8;     // waves per block (2 per SIMD)
constexpr int DELTA = 16;    // global steps between block barriers
constexpr int LAM   = 80;    // per-wave lag (= 63 + DELTA + 1)
constexpr int SMAX  = 574;   // last local step per wave (inclusive)
constexpr int NSUP  = 71;    // supersteps; cover g = 0..1135 >= 1134

// lane u <- lane u-1 (wave_shr:1; lane 0 keeps own value, always overridden)
__device__ __forceinline__ float dpp_shr1(float x) {
    const int xi = __builtin_bit_cast(int, x);
    const int r  = __builtin_amdgcn_update_dpp(xi, xi, 0x138, 0xF, 0xF, false);
    return __builtin_bit_cast(float, r);
}

// Single forward pass computing (R, Rdot): Rdot = JVP of soft-DTW in the
// direction Omega_ij = (i-j)^2; loss_temporal = Rdot[N,N]/N^2.
// 8 staggered waves per batch; wave w owns rows [64w,64w+64); lane u owns row
// 64w+u. Local step s handles column c = s-u. Wave w reads boundary ring[w]
// (ring[0] prefilled = top border), writes ring[w+1]. Ring writes are
// all-lane: lane u writes entry c at slot c+u, so lane63's canonical value
// lands last (slot c+63) and the consumer reads >=17 slots later.
__global__ __launch_bounds__(512)
void dilate_jvp8(const float* __restrict__ input,
                 const float* __restrict__ target,
                 float* __restrict__ partials,
                 int b0)
{
    __shared__ float  sx[kN + 16];
    __shared__ float2 ring[W + 1][128];   // {R, Rdot} row-boundaries
    __shared__ float  sred[W];

    const int tid = (int)threadIdx.x;
    const int w = tid >> 6, u = tid & 63;
    const bool topw = (w == 0);
    const int b = b0 + (int)blockIdx.x;
    const int sOff = w * LAM;

    sx[tid] = input[(size_t)b * kN + tid];
    if (tid < 16)  sx[kN + tid] = 0.0f;                    // pad (FULL path)
    if (tid < 128) ring[0][tid] = make_float2(kBig, 0.0f); // top border
    const float tk = target[(size_t)b * kN + tid];

    // normalized exponential time weight for row tid
    float ew = exp2f(kWexp * (float)tid);
    float es = ew;
    #pragma unroll
    for (int off = 32; off; off >>= 1) es += __shfl_xor(es, off);
    if (u == 0) sred[w] = es;
    __syncthreads();
    float tot = 0.0f;
    #pragma unroll
    for (int q = 0; q < W; ++q) tot += sred[q];
    const float wk = ew * (512.0f / tot);

    // ================= forward soft-DTW with dual (JVP) =================
    float C0 = kBig, C0d = 0.0f;                 // own row, previous column
    float aval = kBig, bval = kBig;              // row above: cols c-1, c
    float avald = 0.0f, bvald = 0.0f;
    float2 rp = make_float2(kBig, 0.0f);         // ring value of previous slot
    float2 rn = make_float2(kBig, 0.0f);         // prefetched ring (next slot)
    float xj  = sx[0];
    float xjn = sx[(u == 0) ? 1 : 0];
    float fdr = (float)(64 * w + 2 * u);         // i - j, rolls down by 1/slot

    for (int m = 0; m < NSUP; ++m) {
        const int base = m * DELTA - sOff;
        if (base >= 63 && base <= 511 - (DELTA - 1)) {
            // ---------- FULL: all lanes valid for all 16 slots ----------
            #pragma unroll
            for (int dg = 0; dg < DELTA; ++dg) {
                const int s = base + dg;
                const float2 rc = rn;
                rn = ring[w][(s + 1) & 127];
                float Bcur = bval, Bd = bvald, Acur = aval, Ad = avald;
                if (u == 0) { Bcur = rc.x; Bd = rc.y; Acur = rp.x; Ad = rp.y; }
                rp = rc;
                const float m0  = fminf(Bcur, fminf(Acur, C0));
                const float mk0 = m0 * kKexp;
                const float eA = exp2f(fmaf(-kKexp, Acur, mk0));
                const float eB = exp2f(fmaf(-kKexp, Bcur, mk0));
                const float eC = exp2f(fmaf(-kKexp, C0,   mk0));
                const float ss = eA + eB + eC;
                const float ri = __builtin_amdgcn_rcpf(ss);
                const float dx = tk - xj;
                const float cur = fmaf(wk * dx, dx,
                                       fmaf(-kGLn2, __log2f(ss), m0));
                const float sd = fmaf(eA, Ad, fmaf(eB, Bd, eC * C0d));
                const float curd = fmaf(ri, sd, fdr * fdr);
                C0 = cur; C0d = curd;
                ring[w + 1][(s - u) & 127] = make_float2(cur, curd);
                aval = bval; avald = bvald;
                bval = dpp_shr1(cur); bvald = dpp_shr1(curd);
                xj = xjn;
                xjn = sx[s + 2 - u];
                fdr -= 1.0f;
            }
        } else if (base + DELTA - 1 >= -1 && base <= SMAX) {
            // ---------- CHECKED: entry/exit ramp ----------
            #pragma unroll
            for (int dg = 0; dg < DELTA; ++dg) {
                const int s = base + dg;
                if (s >= -1 && s <= SMAX) {
                    const float2 rc = rn;
                    rn = ring[w][(s + 1) & 127];
                    if (s >= 0) {
                        const int c = s - u;
                        const bool valid = (c >= 0) & (c <= 511);
                        float Bcur = bval, Bd = bvald;
                        float Acur = aval, Ad = avald;
                        if (u == 0) {
                            Bcur = rc.x; Bd = rc.y;
                            Acur = rp.x; Ad = rp.y;
                            if (topw && s == 0) Acur = 0.0f;
                        }
                        rp = rc;
                        const float m0  = fminf(Bcur, fminf(Acur, C0));
                        const float mk0 = m0 * kKexp;
                        const float eA = exp2f(fmaf(-kKexp, Acur, mk0));
                        const float eB = exp2f(fmaf(-kKexp, Bcur, mk0));
                        const float eC = exp2f(fmaf(-kKexp, C0,   mk0));
                        const float ss = eA + eB + eC;
                        const float ri = __builtin_amdgcn_rcpf(ss);
                        const float dx = tk - xj;
                        float cur = fmaf(wk * dx, dx,
                                         fmaf(-kGLn2, __log2f(ss), m0));
                        const float sd = fmaf(eA, Ad, fmaf(eB, Bd, eC * C0d));
                        float curd = fmaf(ri, sd, fdr * fdr);
                        cur  = valid ? cur  : kBig;
                        curd = valid ? curd : 0.0f;
                        C0 = cur; C0d = curd;
                        ring[w + 1][c & 127] = make_float2(cur, curd);
                        aval = bval; avald = bvald;
                        bval = dpp_shr1(cur); bvald = dpp_shr1(curd);
                        xj = xjn;
                        int cc = c + 2; cc = cc < 0 ? 0 : (cc > 511 ? 511 : cc);
                        xjn = sx[cc];
                        fdr -= 1.0f;
                    }
                }
            }
        }
        __syncthreads();
    }

    // tid 511 (wave 7, lane 63) holds R[512][512] and Rdot[512][512]
    if (tid == 511) {
        const float temporal = C0d * (1.0f / (512.0f * 512.0f));
        partials[b] = (kAlpha * C0 + (1.0f - kAlpha) * temporal)
                    * (1.0f / (float)kB);
    }
}

__global__ void dilate_finalize(const float* __restrict__ partials,
                                float* __restrict__ out) {
    float v = partials[threadIdx.x];   // 64 threads = one wave
    #pragma unroll
    for (int off = 32; off > 0; off >>= 1) v += __shfl_down(v, off);
    if (threadIdx.x == 0) out[0] = v;
}

} // namespace

extern "C" void kernel_launch(void* const* d_in, const int* in_sizes, int n_in,
                              void* d_out, int out_size, void* d_ws, size_t ws_size,
                              hipStream_t stream) {
    (void)in_sizes; (void)n_in; (void)out_size; (void)ws_size;
    const float* input  = (const float*)d_in[0];
    const float* target = (const float*)d_in[1];
    float* out      = (float*)d_out;
    float* partials = (float*)d_ws;    // kB floats

    hipLaunchKernelGGL(dilate_jvp8, dim3(kB), dim3(512), 0, stream,
                       input, target, partials, 0);
    hipLaunchKernelGGL(dilate_finalize, dim3(1), dim3(64), 0, stream,
                       partials, out);
}

// Round 15
// 201.162 us; speedup vs baseline: 1.3858x; 1.0697x over previous
//
#include <hip/hip_runtime.h>
#include <cstddef>
#include <cstdint>

namespace {

constexpr int   kN = 512;
constexpr int   kB = 64;
constexpr float kAlpha = 0.8f;
constexpr float kBig  = 1e8f;
constexpr float kKexp = 144.26950408889634f;    // (1/gamma) * log2(e)
constexpr float kGLn2 = 0.006931471805599453f;  // gamma * ln(2)
constexpr float kWexp = 0.07213475204444817f;   // G * log2(e)

constexpr int W     = 8;     // waves per block (2 per SIMD)
constexpr int DELTA = 16;    // global steps between block barriers
constexpr int LAM   = 80;    // per-wave lag (63 skew + DELTA + 1)
constexpr int SMAX  = 574;   // last local step per wave (inclusive)
constexpr int NSUP  = 71;    // supersteps cover g = 0..1135 >= 1134
constexpr int BUFE  = 592;   // boundary buffer entries per band (no wrap)

// result lane i = src[i-1] for i>=1; lane 0 = oldv[0]  (wave_shr:1 fold)
__device__ __forceinline__ float dpp_oldshr1(float oldv, float src) {
    const int oi = __builtin_bit_cast(int, oldv);
    const int si = __builtin_bit_cast(int, src);
    const int r  = __builtin_amdgcn_update_dpp(oi, si, 0x138, 0xF, 0xF, false);
    return __builtin_bit_cast(float, r);
}

// Single forward pass computing (R, Rdot): Rdot = JVP of soft-DTW in the
// direction Omega_ij = (i-j)^2; loss_temporal = Rdot[N,N]/N^2.
// 8 staggered waves per batch; wave w owns rows [64w,64w+64); lane u owns row
// 64w+u; local step s handles column c = s-u. Wave w reads boundary buf[w]
// (row 64w; buf[0] prefilled border) and writes buf[w+1] (row 64w+64 —
// all-lane writes, lane63's canonical value lands last). Canonical write of
// entry e at global step e+63+80w; consumer prefetch-read at e+79+80w —
// always separated by >=1 superstep barrier (race-free).
// x pipeline is depth 2: xjn loaded at end of step s is consumed at step s+2,
// hence index s+2-u.
__global__ __launch_bounds__(512, 2)
void dilate_jvp8(const float* __restrict__ input,
                 const float* __restrict__ target,
                 float* __restrict__ partials,
                 int b0)
{
    __shared__ float  sx[kN + 16];
    __shared__ float2 buf[W + 1][BUFE];
    __shared__ float  sred[W];

    const int tid = (int)threadIdx.x;
    const int w = tid >> 6, u = tid & 63;
    const bool topw = (w == 0);
    const int b = b0 + (int)blockIdx.x;
    const int sOff = w * LAM;

    sx[tid] = input[(size_t)b * kN + tid];
    if (tid < 16) sx[kN + tid] = 0.0f;
    for (int i = tid; i < BUFE; i += 512) buf[0][i] = make_float2(kBig, 0.0f);
    const float tk = target[(size_t)b * kN + tid];

    // normalized exponential time weight for row tid
    float ew = exp2f(kWexp * (float)tid);
    float es = ew;
    #pragma unroll
    for (int off = 32; off; off >>= 1) es += __shfl_xor(es, off);
    if (u == 0) sred[w] = es;
    __syncthreads();
    float tot = 0.0f;
    #pragma unroll
    for (int q = 0; q < W; ++q) tot += sred[q];
    const float wk = ew * (512.0f / tot);

    // ================= forward soft-DTW with dual (JVP) =================
    float C0 = kBig, C0d = 0.0f;                 // own row, previous column
    float bval = kBig, bvald = 0.0f;             // B: lane0=buf[s], else cur[u-1]
    float aval = (topw && u == 0) ? 0.0f : kBig; // A: rolls from bval
    float avald = 0.0f;
    float xj = sx[0], xjn = sx[(u == 0) ? 1 : 0];
    float fdr = (float)(64 * w + 2 * u);         // i - j, -1 per slot
    const float2* __restrict__ bufP = buf[w];
    float2* __restrict__ bufN = buf[w + 1];

    for (int m = 0; m < NSUP; ++m) {
        const int base = m * DELTA - sOff;
        if (base >= 64 && base <= 496) {
            // ---------- FULL: every lane valid for all 16 slots ----------
            #pragma unroll
            for (int dg = 0; dg < DELTA; ++dg) {
                const int s = base + dg;
                const float m0 = fminf(bval, fminf(aval, C0));
                const float mk = m0 * kKexp;
                const float eA = exp2f(fmaf(-kKexp, aval, mk));
                const float eB = exp2f(fmaf(-kKexp, bval, mk));
                const float eC = exp2f(fmaf(-kKexp, C0,   mk));
                const float ss = eA + eB + eC;
                const float ri = __builtin_amdgcn_rcpf(ss);
                const float dx = tk - xj;
                const float cur = fmaf(wk * dx, dx,
                                       fmaf(-kGLn2, __log2f(ss), m0));
                const float sd = fmaf(eA, avald, fmaf(eB, bvald, eC * C0d));
                const float curd = fmaf(ri, sd, fdr * fdr);
                C0 = cur; C0d = curd;
                bufN[s - u] = make_float2(cur, curd);
                aval = bval; avald = bvald;
                const float2 rn = bufP[s + 1];
                bval  = dpp_oldshr1(rn.x, cur);
                bvald = dpp_oldshr1(rn.y, curd);
                xj = xjn;
                xjn = sx[s + 2 - u];
                fdr -= 1.0f;
            }
        } else if (base >= -DELTA && base <= SMAX) {
            // ---------- CHECKED: entry/exit ramps ----------
            #pragma unroll
            for (int dg = 0; dg < DELTA; ++dg) {
                const int s = base + dg;
                if (s == -1) {
                    const float2 r0 = bufP[0];
                    bval  = dpp_oldshr1(r0.x, kBig);
                    bvald = dpp_oldshr1(r0.y, 0.0f);
                } else if (s >= 0 && s <= SMAX) {
                    const int c = s - u;
                    const bool valid = (c >= 0) & (c <= 511);
                    const float m0 = fminf(bval, fminf(aval, C0));
                    const float mk = m0 * kKexp;
                    const float eA = exp2f(fmaf(-kKexp, aval, mk));
                    const float eB = exp2f(fmaf(-kKexp, bval, mk));
                    const float eC = exp2f(fmaf(-kKexp, C0,   mk));
                    const float ss = eA + eB + eC;
                    const float ri = __builtin_amdgcn_rcpf(ss);
                    const float dx = tk - xj;
                    float cur = fmaf(wk * dx, dx,
                                     fmaf(-kGLn2, __log2f(ss), m0));
                    const float sd = fmaf(eA, avald, fmaf(eB, bvald, eC * C0d));
                    float curd = fmaf(ri, sd, fdr * fdr);
                    cur  = valid ? cur  : kBig;
                    curd = valid ? curd : 0.0f;
                    C0 = cur; C0d = curd;
                    if (c >= 0) bufN[c] = make_float2(cur, curd);
                    aval = bval; avald = bvald;
                    const float2 rn = bufP[s + 1];
                    bval  = dpp_oldshr1(rn.x, cur);
                    bvald = dpp_oldshr1(rn.y, curd);
                    xj = xjn;
                    int cc = s + 2 - u;
                    cc = cc < 0 ? 0 : (cc > 511 ? 511 : cc);
                    xjn = sx[cc];
                    fdr -= 1.0f;
                }
            }
        }
        __syncthreads();
    }

    // tid 511 (wave 7, lane 63) holds R[512][512] and Rdot[512][512]
    if (tid == 511) {
        const float temporal = C0d * (1.0f / (512.0f * 512.0f));
        partials[b] = (kAlpha * C0 + (1.0f - kAlpha) * temporal)
                    * (1.0f / (float)kB);
    }
}

__global__ void dilate_finalize(const float* __restrict__ partials,
                                float* __restrict__ out) {
    float v = partials[threadIdx.x];   // 64 threads = one wave
    #pragma unroll
    for (int off = 32; off > 0; off >>= 1) v += __shfl_down(v, off);
    if (threadIdx.x == 0) out[0] = v;
}

} // namespace

extern "C" void kernel_launch(void* const* d_in, const int* in_sizes, int n_in,
                              void* d_out, int out_size, void* d_ws, size_t ws_size,
                              hipStream_t stream) {
    (void)in_sizes; (void)n_in; (void)out_size; (void)ws_size;
    const float* input  = (const float*)d_in[0];
    const float* target = (const float*)d_in[1];
    float* out      = (float*)d_out;
    float* partials = (float*)d_ws;    // kB floats

    hipLaunchKernelGGL(dilate_jvp8, dim3(kB), dim3(512), 0, stream,
                       input, target, partials, 0);
    hipLaunchKernelGGL(dilate_finalize, dim3(1), dim3(64), 0, stream,
                       partials, out);
}